// Round 7
// baseline (541.267 us; speedup 1.0000x reference)
//
#include <hip/hip_runtime.h>

// VQ-VAE VectorQuantizer forward, MI355X (gfx950), fp32.
// N=32768 points x D=64 dims, K=1024 codes.
// Out: [0]=loss, [1..QE]=quantized [B,D,H,W], [+..]=indices [B,H*W] as f32.
//
// R11: x operand via the SCALAR pipe. Evidence R4-R10: duration ~= LDS-pipe
// time + VALU time (no overlap); x in VGPRs spills (128-cap at 1024thr:
// R8/R10 FETCH/WRITE blowups), x via readlane costs VALU (R7), x from
// global VMEM at distance 0 exposes L2 latency (R6). x per (wave,d) is 8
// wave-uniform floats -> s_load_dwordx8 into SGPRs (v_fmac takes one SGPR
// src): zero LDS instrs, zero VGPRs, zero VALU for x. One readfirstlane'd
// base; all 64 d-offsets fit s_load's 21-bit imm. Loads in 4-dd groups,
// asm enters AND exits with lgkmcnt(0) drained so the compiler's own
// ds_read waitcnt bookkeeping stays correct (lgkm completes out-of-order
// across SMEM/DS -- never leave hidden ops pending).
// LDS drops to 2 e-reads/thread/dd: 4096 wave-b128/CU ~49K cyc vs VALU
// ~94K. xT kept for bit-exact x2 + epilogue only.
// All per-(point,code) fmaf chains (i-outer/j-inner, d-ascending), fold
// exprs, tie-breaks, loss partition/order verbatim R9 (passed, absmax 0).

constexpr int D_   = 64;
constexpr int HW   = 1024;     // H*W
constexpr int K_   = 1024;
constexpr int PTS  = 128;      // points per block
constexpr int CK   = 512;      // codes per chunk (2 chunks)
constexpr int DH   = 32;       // dims per stage half
constexpr int SP   = 132;      // xT row stride (floats)
constexpr int QE   = 2097152;
constexpr int IDX_OFF = 1 + QE;

typedef int v8i __attribute__((ext_vector_type(8)));

// 4 consecutive-d x rows (8 floats each, wave-uniform) -> SGPRs.
// BYTEOFF is compile-time; d-stride is HW*4 = 4096 bytes.
template <int BYTEOFF>
__device__ __forceinline__ void xload4(unsigned long long base,
                                       v8i& q0, v8i& q1, v8i& q2, v8i& q3) {
  asm volatile(
      "s_waitcnt lgkmcnt(0)\n\t"          // drain compiler ds ops (bookkeeping)
      "s_load_dwordx8 %0, %4, %5\n\t"
      "s_load_dwordx8 %1, %4, %6\n\t"
      "s_load_dwordx8 %2, %4, %7\n\t"
      "s_load_dwordx8 %3, %4, %8\n\t"
      "s_waitcnt lgkmcnt(0)"              // x ready; exit with lgkm == 0
      : "=&s"(q0), "=&s"(q1), "=&s"(q2), "=&s"(q3)
      : "s"(base), "n"(BYTEOFF), "n"(BYTEOFF + 4096), "n"(BYTEOFF + 8192),
        "n"(BYTEOFF + 12288));
}

// one d-step: 2 e-reads (LDS) + 64 fmaf with x from SGPRs (QV = v8i)
#define DD1(QV)                                                        \
  {                                                                    \
    float4 e0 = *(const float4*)(ep);        /* codes lane*8+0..3 */   \
    float4 e1 = *(const float4*)(ep + 256);  /* codes lane*8+4..7 */   \
    ep += CK;                                                          \
    float ef[8] = {e0.x, e0.y, e0.z, e0.w, e1.x, e1.y, e1.z, e1.w};    \
    _Pragma("unroll") for (int i = 0; i < 8; ++i) {                    \
      float xsv = __int_as_float((QV)[i]);                             \
      _Pragma("unroll") for (int j = 0; j < 8; ++j)                    \
          acc[i][j] = fmaf(xsv, ef[j], acc[i][j]);                     \
    }                                                                  \
  }

#define GRP(OFF)                                                       \
  {                                                                    \
    v8i qa, qb, qc, qd;                                                \
    xload4<OFF>(xbase, qa, qb, qc, qd);                                \
    DD1(qa) DD1(qb) DD1(qc) DD1(qd)                                    \
  }

// 32 d-steps of one stage; DHI = dh (0/1) compile-time for the imm offsets
template <int DHI>
__device__ __forceinline__ void stage32(float (&acc)[8][8], const float* eTs,
                                        int lane, unsigned long long xbase) {
  const float* ep = eTs + lane * 4;   // lane-contiguous 16B: conflict-free
  GRP(DHI * 131072 + 0 * 16384)
  GRP(DHI * 131072 + 1 * 16384)
  GRP(DHI * 131072 + 2 * 16384)
  GRP(DHI * 131072 + 3 * 16384)
  GRP(DHI * 131072 + 4 * 16384)
  GRP(DHI * 131072 + 5 * 16384)
  GRP(DHI * 131072 + 6 * 16384)
  GRP(DHI * 131072 + 7 * 16384)
}

__global__ __launch_bounds__(1024, 4) void vq_main_kernel(
    const float* __restrict__ in, const float* __restrict__ emb,
    float* __restrict__ out, float* __restrict__ loss_acc,
    unsigned* __restrict__ cnt) {
  __shared__ float eTs[DH * CK];     // 64 KB; row d' = [h][g][q] swizzle
  __shared__ float xT[D_ * SP];      // 33.8 KB, [d][p]: x2 + epilogue only
  __shared__ float e2s[K_];          // 4 KB
  __shared__ float x2s[PTS];
  __shared__ int   idx_sel[PTS];
  __shared__ float redbuf[8];

  const int t    = threadIdx.x;
  const int lane = t & 63;           // code group: 8 codes
  const int wv   = t >> 6;           // wave 0..15 = point group: 8 points
  const int p0   = wv * 8;
  const int blk  = blockIdx.x;
  const int b    = blk >> 3;         // 8 blocks per image
  const int hw0  = (blk & 7) * PTS;
  const float* inb = in + b * (D_ * HW) + hw0;

  // staging role: chunk-local code kl, dim-16-group h within the 32-d half
  const int kl = t & 511;
  const int h  = t >> 9;             // 0/1 (wave-uniform)
  const int pos = ((kl >> 2) & 1) * 256 + (kl >> 3) * 4 + (kl & 3);

  // wave-uniform x base (32B-aligned): in + b*64K + hw0 + p0
  unsigned long long xaddr = (unsigned long long)(const void*)(inb + p0);
  unsigned xlo = __builtin_amdgcn_readfirstlane((unsigned)xaddr);
  unsigned xhi = __builtin_amdgcn_readfirstlane((unsigned)(xaddr >> 32));
  const unsigned long long xbase = ((unsigned long long)xhi << 32) | xlo;

  // ---- stage x tile -> xT[d][p] (coalesced float4; also warms L2 for x) ----
#pragma unroll
  for (int i = 0; i < 2; ++i) {
    int fi = t + i * 1024;                // 0..2047
    int d  = fi >> 5, p4 = fi & 31;
    *(float4*)(&xT[d * SP + p4 * 4]) = *(const float4*)(inb + d * HW + p4 * 4);
  }

  // ---- e2s: 1 code/thread, body identical to R4..R10 (rounding!) ----
  {
    const float4* e4 = (const float4*)(emb + t * 64);
    float s = 0.f;
#pragma unroll
    for (int q = 0; q < 16; ++q) {
      float4 v = e4[q];
      s += v.x * v.x; s += v.y * v.y; s += v.z * v.z; s += v.w * v.w;
    }
    e2s[t] = s;
  }

  // ---- stage (c=0, dh=0) into eTs ----
  {
    const float4* g = (const float4*)(emb + kl * 64 + h * 16);
    float4 v0 = g[0], v1 = g[1], v2 = g[2], v3 = g[3];
    int dq = h * 16;
    eTs[(dq + 0) * CK + pos] = v0.x; eTs[(dq + 1) * CK + pos] = v0.y;
    eTs[(dq + 2) * CK + pos] = v0.z; eTs[(dq + 3) * CK + pos] = v0.w;
    eTs[(dq + 4) * CK + pos] = v1.x; eTs[(dq + 5) * CK + pos] = v1.y;
    eTs[(dq + 6) * CK + pos] = v1.z; eTs[(dq + 7) * CK + pos] = v1.w;
    eTs[(dq + 8) * CK + pos] = v2.x; eTs[(dq + 9) * CK + pos] = v2.y;
    eTs[(dq +10) * CK + pos] = v2.z; eTs[(dq +11) * CK + pos] = v2.w;
    eTs[(dq +12) * CK + pos] = v3.x; eTs[(dq +13) * CK + pos] = v3.y;
    eTs[(dq +14) * CK + pos] = v3.z; eTs[(dq +15) * CK + pos] = v3.w;
  }
  __syncthreads();

  // ---- x2[p] from xT (sequential d fmaf chain — identical values) ----
  if (t < PTS) {
    float s = 0.f;
#pragma unroll 8
    for (int d = 0; d < D_; ++d) { float xv = xT[d * SP + t]; s = fmaf(xv, xv, s); }
    x2s[t] = s;
  }
  __syncthreads();

  float minv[8]; int mini[8];
#pragma unroll
  for (int i = 0; i < 8; ++i) { minv[i] = 3.4e38f; mini[i] = 0; }

  // ---- K loop: 2 chunks of 512 codes, each in two 32-d stages ----
#pragma unroll 1
  for (int c = 0; c < 2; ++c) {
    float acc[8][8];
#pragma unroll
    for (int i = 0; i < 8; ++i)
#pragma unroll
      for (int j = 0; j < 8; ++j) acc[i][j] = 0.f;

    // ---- stage s = c*2 (dh = 0) ----
    stage32<0>(acc, eTs, lane, xbase);
    {
      const int s = c * 2;
      if (s < 3) {
        __syncthreads();   // all waves done reading this eTs stage
        const int cn = (s + 1) >> 1, dn = (s + 1) & 1;
        const float4* g =
            (const float4*)(emb + (cn * CK + kl) * 64 + dn * DH + h * 16);
        float4 v0 = g[0], v1 = g[1], v2 = g[2], v3 = g[3];
        int dq = h * 16;
        eTs[(dq + 0) * CK + pos] = v0.x; eTs[(dq + 1) * CK + pos] = v0.y;
        eTs[(dq + 2) * CK + pos] = v0.z; eTs[(dq + 3) * CK + pos] = v0.w;
        eTs[(dq + 4) * CK + pos] = v1.x; eTs[(dq + 5) * CK + pos] = v1.y;
        eTs[(dq + 6) * CK + pos] = v1.z; eTs[(dq + 7) * CK + pos] = v1.w;
        eTs[(dq + 8) * CK + pos] = v2.x; eTs[(dq + 9) * CK + pos] = v2.y;
        eTs[(dq +10) * CK + pos] = v2.z; eTs[(dq +11) * CK + pos] = v2.w;
        eTs[(dq +12) * CK + pos] = v3.x; eTs[(dq +13) * CK + pos] = v3.y;
        eTs[(dq +14) * CK + pos] = v3.z; eTs[(dq +15) * CK + pos] = v3.w;
        __syncthreads();
      }
    }

    // ---- stage s = c*2+1 (dh = 1) ----
    stage32<1>(acc, eTs, lane, xbase);
    {
      const int s = c * 2 + 1;
      if (s < 3) {
        __syncthreads();
        const int cn = (s + 1) >> 1, dn = (s + 1) & 1;
        const float4* g =
            (const float4*)(emb + (cn * CK + kl) * 64 + dn * DH + h * 16);
        float4 v0 = g[0], v1 = g[1], v2 = g[2], v3 = g[3];
        int dq = h * 16;
        eTs[(dq + 0) * CK + pos] = v0.x; eTs[(dq + 1) * CK + pos] = v0.y;
        eTs[(dq + 2) * CK + pos] = v0.z; eTs[(dq + 3) * CK + pos] = v0.w;
        eTs[(dq + 4) * CK + pos] = v1.x; eTs[(dq + 5) * CK + pos] = v1.y;
        eTs[(dq + 6) * CK + pos] = v1.z; eTs[(dq + 7) * CK + pos] = v1.w;
        eTs[(dq + 8) * CK + pos] = v2.x; eTs[(dq + 9) * CK + pos] = v2.y;
        eTs[(dq +10) * CK + pos] = v2.z; eTs[(dq +11) * CK + pos] = v2.w;
        eTs[(dq +12) * CK + pos] = v3.x; eTs[(dq +13) * CK + pos] = v3.y;
        eTs[(dq +14) * CK + pos] = v3.z; eTs[(dq +15) * CK + pos] = v3.w;
        __syncthreads();
      }
    }

    // fold: u = fl(fl(x2 - 2*dot) + e2) — identical expression/order
    float x2v[8];
    {
      float4 xa2 = *(const float4*)&x2s[p0];     // broadcast
      float4 xb2 = *(const float4*)&x2s[p0 + 4];
      x2v[0]=xa2.x; x2v[1]=xa2.y; x2v[2]=xa2.z; x2v[3]=xa2.w;
      x2v[4]=xb2.x; x2v[5]=xb2.y; x2v[6]=xb2.z; x2v[7]=xb2.w;
    }
    float e2f[8];
    {
      const float4* p4 = (const float4*)&e2s[c * CK + lane * 8];
      float4 v0 = p4[0], v1 = p4[1];
      e2f[0]=v0.x; e2f[1]=v0.y; e2f[2]=v0.z; e2f[3]=v0.w;
      e2f[4]=v1.x; e2f[5]=v1.y; e2f[6]=v1.z; e2f[7]=v1.w;
    }
#pragma unroll
    for (int j = 0; j < 8; ++j) {
      int cg = c * CK + lane * 8 + j;            // ascending within thread
      float e2v = e2f[j];
#pragma unroll
      for (int i = 0; i < 8; ++i) {
        float u = fmaf(-2.f, acc[i][j], x2v[i]) + e2v;
        if (u < minv[i]) { minv[i] = u; mini[i] = cg; }
      }
    }
  }

  // ---- argmin: full-wave butterfly (each wave owns its 8 points) ----
#pragma unroll
  for (int i = 0; i < 8; ++i) {
    float v = minv[i]; int ix = mini[i];
#pragma unroll
    for (int off = 1; off < 64; off <<= 1) {
      float vo = __shfl_xor(v, off);
      int   io = __shfl_xor(ix, off);
      if (vo < v || (vo == v && io < ix)) { v = vo; ix = io; }  // tie -> lower
    }
    if (lane == 0) idx_sel[p0 + i] = ix;
  }
  __syncthreads();

  if (t < PTS) out[IDX_OFF + blk * PTS + t] = (float)idx_sel[t];

  // ---- fused epilogue: gather codes, loss partial, store quantized ----
  // t<512 with R4's EXACT per-thread partition/order -> loss bits identical.
  // x read from xT (bitwise copy of inb) -> same values as global reads.
  float* outq = out + 1 + b * (D_ * HW) + hw0;
  float lp = 0.f;
  if (t < 512) {
#pragma unroll
    for (int i = 0; i < 4; ++i) {
      int fi = t + i * 512;               // 0..2047
      int p = fi & 127, qd = fi >> 7;     // p contiguous per wave
      int cidx = idx_sel[p];
      float4 q = *(const float4*)(emb + cidx * 64 + qd * 4);
      float xv0 = xT[(qd * 4 + 0) * SP + p];
      float xv1 = xT[(qd * 4 + 1) * SP + p];
      float xv2 = xT[(qd * 4 + 2) * SP + p];
      float xv3 = xT[(qd * 4 + 3) * SP + p];
      float d0 = q.x - xv0, d1 = q.y - xv1, d2 = q.z - xv2, d3 = q.w - xv3;
      lp = fmaf(d0, d0, lp); lp = fmaf(d1, d1, lp);
      lp = fmaf(d2, d2, lp); lp = fmaf(d3, d3, lp);
      outq[(qd * 4 + 0) * HW + p] = xv0 + d0;
      outq[(qd * 4 + 1) * HW + p] = xv1 + d1;
      outq[(qd * 4 + 2) * HW + p] = xv2 + d2;
      outq[(qd * 4 + 3) * HW + p] = xv3 + d3;
    }

    // loss: wave -> block partials in R4's exact order (waves 0..7)
#pragma unroll
    for (int off = 1; off < 64; off <<= 1) lp += __shfl_xor(lp, off);
    if ((t & 63) == 0) redbuf[t >> 6] = lp;
  }
  __syncthreads();
  if (t == 0) {
    float part = 0.f;
#pragma unroll
    for (int w = 0; w < 8; ++w) part += redbuf[w];
    atomicAdd(loss_acc, part);
    __threadfence();
    unsigned old = atomicAdd(cnt, 1u);
    if (old == 255u) {
      __threadfence();
      float total = atomicAdd(loss_acc, 0.0f);  // coherent read-back
      float m = total * (1.0f / 2097152.0f);
      out[0] = m + 0.25f * m;                   // ref op order
    }
  }
}

extern "C" void kernel_launch(void* const* d_in, const int* in_sizes, int n_in,
                              void* d_out, int out_size, void* d_ws, size_t ws_size,
                              hipStream_t stream) {
  const float* in  = (const float*)d_in[0];
  const float* emb = (const float*)d_in[1];
  float* out = (float*)d_out;
  float* loss_acc = (float*)d_ws;                 // ws[0]
  unsigned* cnt   = (unsigned*)d_ws + 4;          // ws[4]

  hipMemsetAsync(d_ws, 0, 64, stream);            // zero accumulator + counter
  vq_main_kernel<<<256, 1024, 0, stream>>>(in, emb, out, loss_acc, cnt);
}

// Round 8
// 139.995 us; speedup vs baseline: 3.8663x; 3.8663x over previous
//
#include <hip/hip_runtime.h>

// VQ-VAE VectorQuantizer forward, MI355X (gfx950), fp32.
// N=32768 points x D=64 dims, K=1024 codes.
// Out: [0]=loss, [1..QE]=quantized [B,D,H,W], [+..]=indices [B,H*W] as f32.
//
// R12: packed fp32 FMA on the R9 skeleton. Evidence R4-R11: duration ~=
// LDS-pipe time (98K cyc/CU: 4 wave-b128/dd x 16 waves x 12cyc x 128
// rounds) + VALU time (95K cyc/SIMD); all x-operand replumbing attempts
// (global R6, readlane R7, VGPR rotation R10, s_load R11) regressed via
// latency or spill. Untouched lever: we issue scalar v_fma_f32 but gfx950
// fp32 peak (157.3TF) requires v_pk_fma_f32 (2-wide, full-rate CDNA2+).
// acc as float2 ext-vectors + __builtin_elementwise_fma -> e-pairs come
// pair-aligned straight from the b128 loads; x splats to both halves.
// Per-element pk_fma rounding == v_fma_f32 and each acc[i][j] keeps its
// d-ascending chain -> bit-exact; fold unpacks to the same scalar exprs.
// Main-loop VALU issue: 64 -> 32 instrs/dd/thread (~65.5K -> ~35K cyc).
// Everything else verbatim R9 (passed, absmax 0). Spill canaries:
// FETCH ~5.2MB / WRITE ~9MB; WRITE>15MB means the v2f arrays spilled.

constexpr int D_   = 64;
constexpr int HW   = 1024;     // H*W
constexpr int K_   = 1024;
constexpr int PTS  = 128;      // points per block
constexpr int CK   = 512;      // codes per chunk (2 chunks)
constexpr int DH   = 32;       // dims per stage half
constexpr int SP   = 132;      // xT row stride (floats)
constexpr int QE   = 2097152;
constexpr int IDX_OFF = 1 + QE;

typedef float v2f __attribute__((ext_vector_type(2)));

__global__ __launch_bounds__(1024, 4) void vq_main_kernel(
    const float* __restrict__ in, const float* __restrict__ emb,
    float* __restrict__ out, float* __restrict__ loss_acc,
    unsigned* __restrict__ cnt) {
  __shared__ float eTs[DH * CK];     // 64 KB; row d' = [h][g][q] swizzle
  __shared__ float xT[D_ * SP];      // 33.8 KB, [d][p]
  __shared__ float e2s[K_];          // 4 KB
  __shared__ float x2s[PTS];
  __shared__ int   idx_sel[PTS];
  __shared__ float redbuf[8];

  const int t    = threadIdx.x;
  const int lane = t & 63;           // code group: 8 codes
  const int wv   = t >> 6;           // wave 0..15 = point group: 8 points
  const int p0   = wv * 8;
  const int blk  = blockIdx.x;
  const int b    = blk >> 3;         // 8 blocks per image
  const int hw0  = (blk & 7) * PTS;
  const float* inb = in + b * (D_ * HW) + hw0;

  // staging role: chunk-local code kl, dim-16-group h within the 32-d half
  const int kl = t & 511;
  const int h  = t >> 9;             // 0/1 (wave-uniform)
  // swizzled column of code kl: codes 8L+j -> col (j<4 ? L*4+j : 256+L*4+j-4)
  const int pos = ((kl >> 2) & 1) * 256 + (kl >> 3) * 4 + (kl & 3);

  // ---- stage x tile -> xT[d][p] (coalesced float4) ----
#pragma unroll
  for (int i = 0; i < 2; ++i) {
    int fi = t + i * 1024;                // 0..2047
    int d  = fi >> 5, p4 = fi & 31;
    *(float4*)(&xT[d * SP + p4 * 4]) = *(const float4*)(inb + d * HW + p4 * 4);
  }

  // ---- e2s: 1 code/thread, body identical to R4..R9 (rounding!) ----
  {
    const float4* e4 = (const float4*)(emb + t * 64);
    float s = 0.f;
#pragma unroll
    for (int q = 0; q < 16; ++q) {
      float4 v = e4[q];
      s += v.x * v.x; s += v.y * v.y; s += v.z * v.z; s += v.w * v.w;
    }
    e2s[t] = s;
  }

  // ---- stage (c=0, dh=0) into eTs ----
  {
    const float4* g = (const float4*)(emb + kl * 64 + h * 16);
    float4 v0 = g[0], v1 = g[1], v2 = g[2], v3 = g[3];
    int dq = h * 16;
    eTs[(dq + 0) * CK + pos] = v0.x; eTs[(dq + 1) * CK + pos] = v0.y;
    eTs[(dq + 2) * CK + pos] = v0.z; eTs[(dq + 3) * CK + pos] = v0.w;
    eTs[(dq + 4) * CK + pos] = v1.x; eTs[(dq + 5) * CK + pos] = v1.y;
    eTs[(dq + 6) * CK + pos] = v1.z; eTs[(dq + 7) * CK + pos] = v1.w;
    eTs[(dq + 8) * CK + pos] = v2.x; eTs[(dq + 9) * CK + pos] = v2.y;
    eTs[(dq +10) * CK + pos] = v2.z; eTs[(dq +11) * CK + pos] = v2.w;
    eTs[(dq +12) * CK + pos] = v3.x; eTs[(dq +13) * CK + pos] = v3.y;
    eTs[(dq +14) * CK + pos] = v3.z; eTs[(dq +15) * CK + pos] = v3.w;
  }
  __syncthreads();

  // ---- x2[p] from xT (sequential d fmaf chain — identical values) ----
  if (t < PTS) {
    float s = 0.f;
#pragma unroll 8
    for (int d = 0; d < D_; ++d) { float xv = xT[d * SP + t]; s = fmaf(xv, xv, s); }
    x2s[t] = s;
  }
  __syncthreads();

  float minv[8]; int mini[8];
#pragma unroll
  for (int i = 0; i < 8; ++i) { minv[i] = 3.4e38f; mini[i] = 0; }

  // ---- K loop: 2 chunks of 512 codes, each in two 32-d stages ----
#pragma unroll 1
  for (int c = 0; c < 2; ++c) {
    v2f acc2[8][4];
#pragma unroll
    for (int i = 0; i < 8; ++i)
#pragma unroll
      for (int jh = 0; jh < 4; ++jh) acc2[i][jh] = (v2f)(0.f);

#pragma unroll 1
    for (int dh = 0; dh < 2; ++dh) {
      const int s = c * 2 + dh;

      const float* ep = &eTs[lane * 4];          // lane-contiguous: conflict-free
      const float* xp = &xT[dh * DH * SP + p0];  // wave-uniform broadcast
#pragma unroll 2
      for (int dd = 0; dd < DH; ++dd) {
        float4 e0 = *(const float4*)(ep);          // codes lane*8+0..3
        float4 e1 = *(const float4*)(ep + 256);    // codes lane*8+4..7
        float4 xa = *(const float4*)(xp);
        float4 xb = *(const float4*)(xp + 4);
        ep += CK; xp += SP;
        float xf[8] = {xa.x, xa.y, xa.z, xa.w, xb.x, xb.y, xb.z, xb.w};
        v2f ef2[4];
        ef2[0] = (v2f){e0.x, e0.y}; ef2[1] = (v2f){e0.z, e0.w};
        ef2[2] = (v2f){e1.x, e1.y}; ef2[3] = (v2f){e1.z, e1.w};
#pragma unroll
        for (int i = 0; i < 8; ++i) {
          v2f xx = (v2f){xf[i], xf[i]};
#pragma unroll
          for (int jh = 0; jh < 4; ++jh)
            acc2[i][jh] = __builtin_elementwise_fma(xx, ef2[jh], acc2[i][jh]);
        }
      }

      if (s < 3) {
        __syncthreads();   // all waves done reading this eTs stage
        // stage next (cn, dn) directly global->LDS (no regs held across compute)
        const int cn = (s + 1) >> 1, dn = (s + 1) & 1;
        const float4* g =
            (const float4*)(emb + (cn * CK + kl) * 64 + dn * DH + h * 16);
        float4 v0 = g[0], v1 = g[1], v2 = g[2], v3 = g[3];
        int dq = h * 16;
        eTs[(dq + 0) * CK + pos] = v0.x; eTs[(dq + 1) * CK + pos] = v0.y;
        eTs[(dq + 2) * CK + pos] = v0.z; eTs[(dq + 3) * CK + pos] = v0.w;
        eTs[(dq + 4) * CK + pos] = v1.x; eTs[(dq + 5) * CK + pos] = v1.y;
        eTs[(dq + 6) * CK + pos] = v1.z; eTs[(dq + 7) * CK + pos] = v1.w;
        eTs[(dq + 8) * CK + pos] = v2.x; eTs[(dq + 9) * CK + pos] = v2.y;
        eTs[(dq +10) * CK + pos] = v2.z; eTs[(dq +11) * CK + pos] = v2.w;
        eTs[(dq +12) * CK + pos] = v3.x; eTs[(dq +13) * CK + pos] = v3.y;
        eTs[(dq +14) * CK + pos] = v3.z; eTs[(dq +15) * CK + pos] = v3.w;
        __syncthreads();
      }
    }

    // fold: u = fl(fl(x2 - 2*dot) + e2) — identical expression/order.
    // acc values are bit-identical to R9's scalars; unpack per (i,j).
    float x2v[8];
    {
      float4 xa2 = *(const float4*)&x2s[p0];     // broadcast
      float4 xb2 = *(const float4*)&x2s[p0 + 4];
      x2v[0]=xa2.x; x2v[1]=xa2.y; x2v[2]=xa2.z; x2v[3]=xa2.w;
      x2v[4]=xb2.x; x2v[5]=xb2.y; x2v[6]=xb2.z; x2v[7]=xb2.w;
    }
    float e2f[8];
    {
      const float4* p4 = (const float4*)&e2s[c * CK + lane * 8];
      float4 v0 = p4[0], v1 = p4[1];
      e2f[0]=v0.x; e2f[1]=v0.y; e2f[2]=v0.z; e2f[3]=v0.w;
      e2f[4]=v1.x; e2f[5]=v1.y; e2f[6]=v1.z; e2f[7]=v1.w;
    }
#pragma unroll
    for (int j = 0; j < 8; ++j) {
      int cg = c * CK + lane * 8 + j;            // ascending within thread
      float e2v = e2f[j];
#pragma unroll
      for (int i = 0; i < 8; ++i) {
        float av = (j & 1) ? acc2[i][j >> 1].y : acc2[i][j >> 1].x;
        float u = fmaf(-2.f, av, x2v[i]) + e2v;
        if (u < minv[i]) { minv[i] = u; mini[i] = cg; }
      }
    }
  }

  // ---- argmin: full-wave butterfly (each wave owns its 8 points) ----
#pragma unroll
  for (int i = 0; i < 8; ++i) {
    float v = minv[i]; int ix = mini[i];
#pragma unroll
    for (int off = 1; off < 64; off <<= 1) {
      float vo = __shfl_xor(v, off);
      int   io = __shfl_xor(ix, off);
      if (vo < v || (vo == v && io < ix)) { v = vo; ix = io; }  // tie -> lower
    }
    if (lane == 0) idx_sel[p0 + i] = ix;
  }
  __syncthreads();

  if (t < PTS) out[IDX_OFF + blk * PTS + t] = (float)idx_sel[t];

  // ---- fused epilogue: gather codes, loss partial, store quantized ----
  // t<512 with R4's EXACT per-thread partition/order -> loss bits identical.
  // x read from xT (bitwise copy of inb) -> same values as global reads.
  float* outq = out + 1 + b * (D_ * HW) + hw0;
  float lp = 0.f;
  if (t < 512) {
#pragma unroll
    for (int i = 0; i < 4; ++i) {
      int fi = t + i * 512;               // 0..2047
      int p = fi & 127, qd = fi >> 7;     // p contiguous per wave
      int cidx = idx_sel[p];
      float4 q = *(const float4*)(emb + cidx * 64 + qd * 4);
      float xv0 = xT[(qd * 4 + 0) * SP + p];
      float xv1 = xT[(qd * 4 + 1) * SP + p];
      float xv2 = xT[(qd * 4 + 2) * SP + p];
      float xv3 = xT[(qd * 4 + 3) * SP + p];
      float d0 = q.x - xv0, d1 = q.y - xv1, d2 = q.z - xv2, d3 = q.w - xv3;
      lp = fmaf(d0, d0, lp); lp = fmaf(d1, d1, lp);
      lp = fmaf(d2, d2, lp); lp = fmaf(d3, d3, lp);
      outq[(qd * 4 + 0) * HW + p] = xv0 + d0;
      outq[(qd * 4 + 1) * HW + p] = xv1 + d1;
      outq[(qd * 4 + 2) * HW + p] = xv2 + d2;
      outq[(qd * 4 + 3) * HW + p] = xv3 + d3;
    }

    // loss: wave -> block partials in R4's exact order (waves 0..7)
#pragma unroll
    for (int off = 1; off < 64; off <<= 1) lp += __shfl_xor(lp, off);
    if ((t & 63) == 0) redbuf[t >> 6] = lp;
  }
  __syncthreads();
  if (t == 0) {
    float part = 0.f;
#pragma unroll
    for (int w = 0; w < 8; ++w) part += redbuf[w];
    atomicAdd(loss_acc, part);
    __threadfence();
    unsigned old = atomicAdd(cnt, 1u);
    if (old == 255u) {
      __threadfence();
      float total = atomicAdd(loss_acc, 0.0f);  // coherent read-back
      float m = total * (1.0f / 2097152.0f);
      out[0] = m + 0.25f * m;                   // ref op order
    }
  }
}

extern "C" void kernel_launch(void* const* d_in, const int* in_sizes, int n_in,
                              void* d_out, int out_size, void* d_ws, size_t ws_size,
                              hipStream_t stream) {
  const float* in  = (const float*)d_in[0];
  const float* emb = (const float*)d_in[1];
  float* out = (float*)d_out;
  float* loss_acc = (float*)d_ws;                 // ws[0]
  unsigned* cnt   = (unsigned*)d_ws + 4;          // ws[4]

  hipMemsetAsync(d_ws, 0, 64, stream);            // zero accumulator + counter
  vq_main_kernel<<<256, 1024, 0, stream>>>(in, emb, out, loss_acc, cnt);
}